// Round 1
// baseline (102.851 us; speedup 1.0000x reference)
//
#include <hip/hip_runtime.h>
#include <math.h>

// RRoIAlign: features (8,32,160,160) f32, rois (1024,6) f32
// out (1024,32,8,64) f32.  POOLED_H=8, POOLED_W=64, SPATIAL_SCALE=0.25
//
// R8: batch->XCD affinity for the gather kernel. ft is 13.1 MB (fp16 NHWC),
// but ONE batch slice is 1.6 MB and fits a single XCD's 4 MB L2. MI355X
// dispatches blocks round-robin over 8 XCDs by linearized block index (%8).
// build_map makes a slot permutation so that slot%8 == batch(roi(slot));
// rroi grid is dim3(N, 8seg) => linear index = seg*N + slot, %8 == slot%8
// (N%8==0), so each XCD gathers from one image slice => L2-resident.
// Overflowing rois (batch count > N/8) take leftover slots (few %).
// Mapping affects locality only, never values: absmax unchanged.
//
// R7: fp16 NHWC intermediate (halves the transpose-trick's HBM overhead).
// Feature fp16 rounding error <= |v|*2^-11 ~ 0.003 << 0.101 threshold.
//
// NUMERICS (frozen since R1): geometry fp contract(off) + reference op order;
// trig double->f32; blend ((w0*a+w1*b)+w2*c)+w3*d contract off. Do not
// re-order. absmax was 0.0 with f32 intermediate; fp16 adds ~3e-3.

#define C_ 32
#define H_ 160
#define W_ 160
#define PH_ 8
#define PW_ 64
#define HW_ (H_ * W_)
#define NB_ (PH_ * PW_)  // 512 bins per roi
#define MAXN_MAP 2048

typedef float nfloat4 __attribute__((ext_vector_type(4)));
typedef _Float16 half4 __attribute__((ext_vector_type(4)));   // 8 B
typedef _Float16 half8 __attribute__((ext_vector_type(8)));   // 16 B

__device__ __forceinline__ void roi_transform(const float* __restrict__ rois,
                                              int n, float* __restrict__ g) {
#pragma clang fp contract(off)
    const float* r = rois + n * 6;
    float bidx = r[0];
    float cx = r[1], cy = r[2], hh = r[3], ww = r[4], ang = r[5];
    float theta = ang * 0.017453292519943295f;
    double td = (double)theta;
    float a = (float)cos(td);
    float s = (float)sin(td);
    float Sx = (ww * 0.25f) / 64.0f;
    float Sy = (hh * 0.25f) / 8.0f;
    float Dx = cx * 0.25f;
    float Dy = cy * 0.25f;
    float M00 = a * Sx;
    float M01 = s * Sy;
    float M02 = ((M00 * -32.0f) + (M01 * -4.0f)) + Dx;
    float M10 = (-s) * Sx;
    float M11 = a * Sy;
    float M12 = ((M10 * -32.0f) + (M11 * -4.0f)) + Dy;
    float* o = g + n * 8;
    o[0] = bidx;
    o[1] = M00; o[2] = M01; o[3] = M02;
    o[4] = M10; o[5] = M11; o[6] = M12;
    o[7] = 0.0f;
}

// Slot permutation: map[slot] = roi, with slot%8 == batch(roi) wherever
// possible (counting sort into 8 buckets; batch b owns slots {8k+b}).
// Overflow rois paired with unused slots in arbitrary (atomic) order --
// mapping is nondeterministic but output values are mapping-independent.
__global__ __launch_bounds__(256) void build_map(
    const float* __restrict__ rois, int* __restrict__ map, int N) {
    __shared__ int s_b[MAXN_MAP];
    __shared__ int s_rank[MAXN_MAP];
    __shared__ unsigned char s_used[MAXN_MAP];
    __shared__ int s_ovf[MAXN_MAP];
    __shared__ int s_free[MAXN_MAP];
    __shared__ int cnt[8];
    __shared__ int ovf_n, free_n;
    int t = threadIdx.x;
    if (t < 8) cnt[t] = 0;
    if (t == 0) { ovf_n = 0; free_n = 0; }
    __syncthreads();
    if ((N > MAXN_MAP) || (N & 7)) {  // generic fallback: identity (correct,
        for (int r = t; r < N; r += 256) map[r] = r;  // just no affinity)
        return;
    }
    for (int r = t; r < N; r += 256) {
        int b = (int)rois[r * 6];
        s_b[r] = b;
        s_rank[r] = atomicAdd(&cnt[b], 1);
        s_used[r] = 0;  // r doubles as slot index (both ranges are N)
    }
    __syncthreads();
    int Kb = N >> 3;
    for (int r = t; r < N; r += 256) {
        int k = s_rank[r];
        if (k < Kb) {
            int slot = k * 8 + s_b[r];
            map[slot] = r;
            s_used[slot] = 1;
        }
    }
    __syncthreads();
    for (int r = t; r < N; r += 256) {
        if (s_rank[r] >= Kb) s_ovf[atomicAdd(&ovf_n, 1)] = r;
        if (!s_used[r]) s_free[atomicAdd(&free_n, 1)] = r;
    }
    __syncthreads();
    for (int j = t; j < ovf_n; j += 256) map[s_free[j]] = s_ovf[j];
}

// NCHW f32 (B,32,25600) -> NHWC fp16 (B,25600,32).
// Blocks (x<ceil(N/256), y==0) also compute roi transforms into g.
__global__ __launch_bounds__(256) void transpose_nhwc(
    const float* __restrict__ feat, _Float16* __restrict__ ft,
    const float* __restrict__ rois, float* __restrict__ g, int N) {
    __shared__ float tile[C_][65];
    int t = threadIdx.x;

    if (blockIdx.y == 0) {
        int n = blockIdx.x * 256 + t;
        if (n < N) roi_transform(rois, n, g);
    }

    int b   = blockIdx.y;
    int hw0 = blockIdx.x * 64;

    // read: 512 float4-units along hw. unit v: c=v>>4, w4=(v&15)*4
#pragma unroll
    for (int i = 0; i < 2; ++i) {
        int v  = i * 256 + t;
        int c  = v >> 4;
        int w4 = (v & 15) * 4;
        const nfloat4 f = __builtin_nontemporal_load(
            (const nfloat4*)&feat[((b * C_ + c) * HW_) + hw0 + w4]);
        tile[c][w4 + 0] = f.x;
        tile[c][w4 + 1] = f.y;
        tile[c][w4 + 2] = f.z;
        tile[c][w4 + 3] = f.w;
    }
    __syncthreads();

    // write: thread t -> pixel p=t>>2, channels c8=(t&3)*8; one 16B store.
    {
        int p  = t >> 2;
        int c8 = (t & 3) * 8;
        half8 o;
#pragma unroll
        for (int k = 0; k < 8; ++k) o[k] = (_Float16)tile[c8 + k][p];
        *(half8*)&ft[((size_t)b * HW_ + hw0 + p) * C_ + c8] = o;
    }
}

// Block = 64 consecutive bins of one roi. 256 threads.
// Grid dim3(N, 8): blockIdx.x = slot (affinity-permuted roi), .y = seg.
__global__ __launch_bounds__(256) void rroi_nhwc(
    const _Float16* __restrict__ ft, const float* __restrict__ g,
    const int* __restrict__ map, float* __restrict__ out) {
    __shared__ int    s_pos[64];
    __shared__ int    s_dxy[64];
    __shared__ float4 s_w[64];
    __shared__ float  s_out[C_ * 65];  // [c][bin], pad 65 (<=2-way, free)

    int n   = map[blockIdx.x];
    int seg = blockIdx.y;
    int t   = threadIdx.x;

    if (t < 64) {
#pragma clang fp contract(off)
        int bin = seg * 64 + t;  // = ph*64+pw
        int pw = bin & 63;
        int ph = bin >> 6;
        const float* gg = g + n * 8;
        int   b   = (int)gg[0];
        float M00 = gg[1], M01 = gg[2], M02 = gg[3];
        float M10 = gg[4], M11 = gg[5], M12 = gg[6];

        float pwf  = (float)pw, phf = (float)ph;
        float pwf1 = pwf + 1.0f, phf1 = phf + 1.0f;
        // corners, reference op order: (M00*px + M01*py) + M02
        float X0 = (M00 * pwf  + M01 * phf ) + M02;
        float X1 = (M00 * pwf  + M01 * phf1) + M02;
        float X2 = (M00 * pwf1 + M01 * phf ) + M02;
        float X3 = (M00 * pwf1 + M01 * phf1) + M02;
        float Y0 = (M10 * pwf  + M11 * phf ) + M12;
        float Y1 = (M10 * pwf  + M11 * phf1) + M12;
        float Y2 = (M10 * pwf1 + M11 * phf ) + M12;
        float Y3 = (M10 * pwf1 + M11 * phf1) + M12;

        float minX = fminf(fminf(X0, X1), fminf(X2, X3));
        float maxX = fmaxf(fmaxf(X0, X1), fmaxf(X2, X3));
        float minY = fminf(fminf(Y0, Y1), fminf(Y2, Y3));
        float maxY = fmaxf(fmaxf(Y0, Y1), fmaxf(Y2, Y3));

        float left   = fmaxf(floorf(minX + 0.5f), 0.0f);
        float right  = fminf(floorf(maxX + 0.5f), (float)(W_ - 1));
        float top    = fmaxf(floorf(minY + 0.5f), 0.0f);
        float bottom = fminf(floorf(maxY + 0.5f), (float)(H_ - 1));

        float bcx = (left + right) * 0.5f;
        float bcy = (top + bottom) * 0.5f;
        float bl = floorf(bcx), br = ceilf(bcx);
        float bt = floorf(bcy), bb = ceilf(bcy);
        float rx = bcx - bl;  // exactly 0 or 0.5
        float ry = bcy - bt;

        bool v_l = (bl > -1.0f) && (bl < (float)W_);
        bool v_r = (br > -1.0f) && (br < (float)W_);
        bool v_t = (bt > -1.0f) && (bt < (float)H_);
        bool v_b = (bb > -1.0f) && (bb < (float)H_);

        float omrx = 1.0f - rx, omry = 1.0f - ry;
        float4 w4;
        w4.x = (v_t && v_l) ? (omrx * omry) : 0.0f;
        w4.y = (v_t && v_r) ? (rx   * omry) : 0.0f;
        w4.z = (v_b && v_l) ? (omrx * ry  ) : 0.0f;
        w4.w = (v_b && v_r) ? (rx   * ry  ) : 0.0f;

        int xl = (int)fminf(fmaxf(bl, 0.0f), (float)(W_ - 1));
        int xr = (int)fminf(fmaxf(br, 0.0f), (float)(W_ - 1));
        int yt = (int)fminf(fmaxf(bt, 0.0f), (float)(H_ - 1));
        int yb = (int)fminf(fmaxf(bb, 0.0f), (float)(H_ - 1));

        s_pos[t] = b * HW_ + yt * W_ + xl;  // NHWC pixel index
        s_dxy[t] = (xr - xl) | (((yb - yt) * W_) << 16);
        s_w[t]   = w4;
    }
    __syncthreads();

    // Gather+blend: 512 units. unit u: bin=u>>3, c4=u&7 (4 channels each).
    // Per corner per wave: 8 bins x 64B contiguous -> coalesced dwordx2.
#pragma unroll
    for (int i = 0; i < 2; ++i) {
#pragma clang fp contract(off)
        int u   = i * 256 + t;
        int bl_ = u >> 3;
        int c4  = u & 7;
        int pos = s_pos[bl_];
        int d   = s_dxy[bl_];
        int dx  = d & 0xffff;
        int dyw = (int)((unsigned)d >> 16);
        float4 w4 = s_w[bl_];

        const half4* f0 = (const half4*)(ft + (size_t)pos * C_) + c4;
        half4 a0 = f0[0];
        half4 a1 = f0[dx * 8];
        half4 a2 = f0[dyw * 8];
        half4 a3 = f0[(dx + dyw) * 8];

        int cb = c4 * 4;
#pragma unroll
        for (int k = 0; k < 4; ++k) {
            float o = ((w4.x * (float)a0[k] + w4.y * (float)a1[k]) +
                       w4.z * (float)a2[k]) +
                      w4.w * (float)a3[k];
            s_out[(cb + k) * 65 + bl_] = o;
        }
    }
    __syncthreads();

    // Store: 512 float4-units along bins. unit v: c=v>>4, b4=(v&15)*4.
    int obase = n * (C_ * NB_) + seg * 64;
#pragma unroll
    for (int i = 0; i < 2; ++i) {
        int v  = i * 256 + t;
        int cc = v >> 4;
        int b4 = (v & 15) * 4;
        nfloat4 o;
        o.x = s_out[cc * 65 + b4 + 0];
        o.y = s_out[cc * 65 + b4 + 1];
        o.z = s_out[cc * 65 + b4 + 2];
        o.w = s_out[cc * 65 + b4 + 3];
        __builtin_nontemporal_store(o, (nfloat4*)&out[obase + cc * NB_ + b4]);
    }
}

// Fallback (R1, known-good): thread per output, full geometry recompute.
__global__ __launch_bounds__(256) void roi_prep(const float* __restrict__ rois,
                                                float* __restrict__ g, int N) {
    int n = blockIdx.x * 256 + threadIdx.x;
    if (n < N) roi_transform(rois, n, g);
}

__global__ __launch_bounds__(256) void rroi_fallback(
    const float* __restrict__ feat, const float* __restrict__ g,
    float* __restrict__ out, int total) {
#pragma clang fp contract(off)
    int idx = blockIdx.x * 256 + threadIdx.x;
    if (idx >= total) return;
    int pw = idx & 63;
    int ph = (idx >> 6) & 7;
    int c  = (idx >> 9) & 31;
    int n  = idx >> 14;
    const float* gg = g + n * 8;
    int   b   = (int)gg[0];
    float M00 = gg[1], M01 = gg[2], M02 = gg[3];
    float M10 = gg[4], M11 = gg[5], M12 = gg[6];
    float pwf  = (float)pw, phf = (float)ph;
    float pwf1 = pwf + 1.0f, phf1 = phf + 1.0f;
    float X0 = (M00 * pwf  + M01 * phf ) + M02;
    float X1 = (M00 * pwf  + M01 * phf1) + M02;
    float X2 = (M00 * pwf1 + M01 * phf ) + M02;
    float X3 = (M00 * pwf1 + M01 * phf1) + M02;
    float Y0 = (M10 * pwf  + M11 * phf ) + M12;
    float Y1 = (M10 * pwf  + M11 * phf1) + M12;
    float Y2 = (M10 * pwf1 + M11 * phf ) + M12;
    float Y3 = (M10 * pwf1 + M11 * phf1) + M12;
    float minX = fminf(fminf(X0, X1), fminf(X2, X3));
    float maxX = fmaxf(fmaxf(X0, X1), fmaxf(X2, X3));
    float minY = fminf(fminf(Y0, Y1), fminf(Y2, Y3));
    float maxY = fmaxf(fmaxf(Y0, Y1), fmaxf(Y2, Y3));
    float left   = fmaxf(floorf(minX + 0.5f), 0.0f);
    float right  = fminf(floorf(maxX + 0.5f), (float)(W_ - 1));
    float top    = fmaxf(floorf(minY + 0.5f), 0.0f);
    float bottom = fminf(floorf(maxY + 0.5f), (float)(H_ - 1));
    float bcx = (left + right) * 0.5f;
    float bcy = (top + bottom) * 0.5f;
    float bl = floorf(bcx), br = ceilf(bcx);
    float bt = floorf(bcy), bb = ceilf(bcy);
    float rx = bcx - bl;
    float ry = bcy - bt;
    const float* fc = feat + (size_t)(b * C_ + c) * HW_;
    auto gat = [&](float yi, float xi) -> float {
        bool valid = (yi > -1.0f) && (xi > -1.0f) && (yi < (float)H_) &&
                     (xi < (float)W_);
        int yc = (int)fminf(fmaxf(yi, 0.0f), (float)(H_ - 1));
        int xc = (int)fminf(fmaxf(xi, 0.0f), (float)(W_ - 1));
        float v = fc[yc * W_ + xc];
        return valid ? v : 0.0f;
    };
    float vlt = gat(bt, bl);
    float vrt = gat(bt, br);
    float vlb = gat(bb, bl);
    float vrb = gat(bb, br);
    float omrx = 1.0f - rx, omry = 1.0f - ry;
    float o = (((omrx * omry) * vlt + (rx * omry) * vrt) + (omrx * ry) * vlb) +
              (rx * ry) * vrb;
    out[idx] = o;
}

extern "C" void kernel_launch(void* const* d_in, const int* in_sizes, int n_in,
                              void* d_out, int out_size, void* d_ws,
                              size_t ws_size, hipStream_t stream) {
    const float* feat = (const float*)d_in[0];
    const float* rois = (const float*)d_in[1];
    float* out = (float*)d_out;
    int N = in_sizes[1] / 6;
    int B = in_sizes[0] / (C_ * HW_);

    size_t gBytes   = ((size_t)N * 8 * sizeof(float) + 255) & ~(size_t)255;
    size_t mapBytes = ((size_t)N * sizeof(int) + 255) & ~(size_t)255;
    size_t ftBytes  = (size_t)B * HW_ * C_ * sizeof(_Float16);
    size_t needed   = gBytes + mapBytes + ftBytes;

    if (ws_size >= needed) {
        float*    g   = (float*)d_ws;
        int*      map = (int*)((char*)d_ws + gBytes);
        _Float16* ft  = (_Float16*)((char*)d_ws + gBytes + mapBytes);
        hipLaunchKernelGGL(build_map, dim3(1), dim3(256), 0, stream, rois, map,
                           N);
        hipLaunchKernelGGL(transpose_nhwc, dim3(HW_ / 64, B), dim3(256), 0,
                           stream, feat, ft, rois, g, N);
        hipLaunchKernelGGL(rroi_nhwc, dim3(N, 8), dim3(256), 0, stream, ft, g,
                           map, out);
    } else {
        float* g = (float*)d_ws;  // N*8 floats
        hipLaunchKernelGGL(roi_prep, dim3((N + 255) / 256), dim3(256), 0,
                           stream, rois, g, N);
        hipLaunchKernelGGL(rroi_fallback, dim3((out_size + 255) / 256),
                           dim3(256), 0, stream, feat, g, out, out_size);
    }
}

// Round 2
// 100.525 us; speedup vs baseline: 1.0231x; 1.0231x over previous
//
#include <hip/hip_runtime.h>
#include <math.h>

// RRoIAlign: features (8,32,160,160) f32, rois (1024,6) f32
// out (1024,32,8,64) f32.  POOLED_H=8, POOLED_W=64, SPATIAL_SCALE=0.25
//
// R9: single-barrier rroi. R8's XCD-affinity was null (gather is not
// L2-miss-bound) -> build_map dropped. New structure: every thread computes
// its own bin's geometry in registers (4x redundant VALU, ~2us chip-wide,
// trivial) -> no s_pos/s_dxy/s_w LDS, no first __syncthreads; gather loads
// issue at block start. Gather widened half4->half8 (16B/lane, 4 loads/thread,
// one pass). Only remaining barrier is before the s_out->global transpose.
//
// R7: fp16 NHWC intermediate (halves the transpose-trick's HBM overhead).
// Feature fp16 rounding error <= |v|*2^-11 ~ 0.003 << 0.101 threshold.
//
// NUMERICS (frozen since R1): geometry fp contract(off) + reference op order;
// trig double->f32; blend ((w0*a+w1*b)+w2*c)+w3*d contract off. Do not
// re-order. absmax was 0.0 with f32 intermediate; fp16 adds ~3e-3.

#define C_ 32
#define H_ 160
#define W_ 160
#define PH_ 8
#define PW_ 64
#define HW_ (H_ * W_)
#define NB_ (PH_ * PW_)  // 512 bins per roi

typedef float nfloat4 __attribute__((ext_vector_type(4)));
typedef _Float16 half8 __attribute__((ext_vector_type(8)));   // 16 B

__device__ __forceinline__ void roi_transform(const float* __restrict__ rois,
                                              int n, float* __restrict__ g) {
#pragma clang fp contract(off)
    const float* r = rois + n * 6;
    float bidx = r[0];
    float cx = r[1], cy = r[2], hh = r[3], ww = r[4], ang = r[5];
    float theta = ang * 0.017453292519943295f;
    double td = (double)theta;
    float a = (float)cos(td);
    float s = (float)sin(td);
    float Sx = (ww * 0.25f) / 64.0f;
    float Sy = (hh * 0.25f) / 8.0f;
    float Dx = cx * 0.25f;
    float Dy = cy * 0.25f;
    float M00 = a * Sx;
    float M01 = s * Sy;
    float M02 = ((M00 * -32.0f) + (M01 * -4.0f)) + Dx;
    float M10 = (-s) * Sx;
    float M11 = a * Sy;
    float M12 = ((M10 * -32.0f) + (M11 * -4.0f)) + Dy;
    float* o = g + n * 8;
    o[0] = bidx;
    o[1] = M00; o[2] = M01; o[3] = M02;
    o[4] = M10; o[5] = M11; o[6] = M12;
    o[7] = 0.0f;
}

// NCHW f32 (B,32,25600) -> NHWC fp16 (B,25600,32).
// Blocks (x<ceil(N/256), y==0) also compute roi transforms into g.
__global__ __launch_bounds__(256) void transpose_nhwc(
    const float* __restrict__ feat, _Float16* __restrict__ ft,
    const float* __restrict__ rois, float* __restrict__ g, int N) {
    __shared__ float tile[C_][65];
    int t = threadIdx.x;

    if (blockIdx.y == 0) {
        int n = blockIdx.x * 256 + t;
        if (n < N) roi_transform(rois, n, g);
    }

    int b   = blockIdx.y;
    int hw0 = blockIdx.x * 64;

    // read: 512 float4-units along hw. unit v: c=v>>4, w4=(v&15)*4
#pragma unroll
    for (int i = 0; i < 2; ++i) {
        int v  = i * 256 + t;
        int c  = v >> 4;
        int w4 = (v & 15) * 4;
        const nfloat4 f = __builtin_nontemporal_load(
            (const nfloat4*)&feat[((b * C_ + c) * HW_) + hw0 + w4]);
        tile[c][w4 + 0] = f.x;
        tile[c][w4 + 1] = f.y;
        tile[c][w4 + 2] = f.z;
        tile[c][w4 + 3] = f.w;
    }
    __syncthreads();

    // write: thread t -> pixel p=t>>2, channels c8=(t&3)*8; one 16B store.
    {
        int p  = t >> 2;
        int c8 = (t & 3) * 8;
        half8 o;
#pragma unroll
        for (int k = 0; k < 8; ++k) o[k] = (_Float16)tile[c8 + k][p];
        *(half8*)&ft[((size_t)b * HW_ + hw0 + p) * C_ + c8] = o;
    }
}

// Block = 64 consecutive bins of one roi. 256 threads, ONE barrier.
// Thread t: bin bl_=t>>2, channels c8=(t&3)*8. Geometry in registers.
__global__ __launch_bounds__(256) void rroi_nhwc(
    const _Float16* __restrict__ ft, const float* __restrict__ g,
    float* __restrict__ out) {
    __shared__ float s_out[C_ * 65];  // [c][bin], pad 65 (2-way, free)

    int blk = blockIdx.x;
    int n   = blk >> 3;   // wave-uniform -> g loads scalarize
    int seg = blk & 7;
    int t   = threadIdx.x;

    int bl_ = t >> 2;          // bin within segment, 0..63
    int c8  = (t & 3) * 8;     // first of 8 channels

    int pos, dx, dyw;
    float4 w4;
    {
#pragma clang fp contract(off)
        int bin = seg * 64 + bl_;  // = ph*64+pw
        int pw = bin & 63;
        int ph = bin >> 6;
        const float* gg = g + n * 8;
        int   b   = (int)gg[0];
        float M00 = gg[1], M01 = gg[2], M02 = gg[3];
        float M10 = gg[4], M11 = gg[5], M12 = gg[6];

        float pwf  = (float)pw, phf = (float)ph;
        float pwf1 = pwf + 1.0f, phf1 = phf + 1.0f;
        // corners, reference op order: (M00*px + M01*py) + M02
        float X0 = (M00 * pwf  + M01 * phf ) + M02;
        float X1 = (M00 * pwf  + M01 * phf1) + M02;
        float X2 = (M00 * pwf1 + M01 * phf ) + M02;
        float X3 = (M00 * pwf1 + M01 * phf1) + M02;
        float Y0 = (M10 * pwf  + M11 * phf ) + M12;
        float Y1 = (M10 * pwf  + M11 * phf1) + M12;
        float Y2 = (M10 * pwf1 + M11 * phf ) + M12;
        float Y3 = (M10 * pwf1 + M11 * phf1) + M12;

        float minX = fminf(fminf(X0, X1), fminf(X2, X3));
        float maxX = fmaxf(fmaxf(X0, X1), fmaxf(X2, X3));
        float minY = fminf(fminf(Y0, Y1), fminf(Y2, Y3));
        float maxY = fmaxf(fmaxf(Y0, Y1), fmaxf(Y2, Y3));

        float left   = fmaxf(floorf(minX + 0.5f), 0.0f);
        float right  = fminf(floorf(maxX + 0.5f), (float)(W_ - 1));
        float top    = fmaxf(floorf(minY + 0.5f), 0.0f);
        float bottom = fminf(floorf(maxY + 0.5f), (float)(H_ - 1));

        float bcx = (left + right) * 0.5f;
        float bcy = (top + bottom) * 0.5f;
        float bl = floorf(bcx), br = ceilf(bcx);
        float bt = floorf(bcy), bb = ceilf(bcy);
        float rx = bcx - bl;  // exactly 0 or 0.5
        float ry = bcy - bt;

        bool v_l = (bl > -1.0f) && (bl < (float)W_);
        bool v_r = (br > -1.0f) && (br < (float)W_);
        bool v_t = (bt > -1.0f) && (bt < (float)H_);
        bool v_b = (bb > -1.0f) && (bb < (float)H_);

        float omrx = 1.0f - rx, omry = 1.0f - ry;
        w4.x = (v_t && v_l) ? (omrx * omry) : 0.0f;
        w4.y = (v_t && v_r) ? (rx   * omry) : 0.0f;
        w4.z = (v_b && v_l) ? (omrx * ry  ) : 0.0f;
        w4.w = (v_b && v_r) ? (rx   * ry  ) : 0.0f;

        int xl = (int)fminf(fmaxf(bl, 0.0f), (float)(W_ - 1));
        int xr = (int)fminf(fmaxf(br, 0.0f), (float)(W_ - 1));
        int yt = (int)fminf(fmaxf(bt, 0.0f), (float)(H_ - 1));
        int yb = (int)fminf(fmaxf(bb, 0.0f), (float)(H_ - 1));

        pos = b * HW_ + yt * W_ + xl;  // NHWC pixel index
        dx  = xr - xl;
        dyw = (yb - yt) * W_;
    }

    // Gather+blend: 16B/lane per corner. Per bin: 4 lanes x 16B = one 64B
    // line per corner -> coalesced dwordx4.
    {
#pragma clang fp contract(off)
        const half8* f0 = (const half8*)(ft + (size_t)pos * C_ + c8);
        half8 a0 = f0[0];
        half8 a1 = f0[dx * 4];
        half8 a2 = f0[dyw * 4];
        half8 a3 = f0[(dx + dyw) * 4];

#pragma unroll
        for (int k = 0; k < 8; ++k) {
            float o = ((w4.x * (float)a0[k] + w4.y * (float)a1[k]) +
                       w4.z * (float)a2[k]) +
                      w4.w * (float)a3[k];
            s_out[(c8 + k) * 65 + bl_] = o;
        }
    }
    __syncthreads();

    // Store: 512 float4-units along bins. unit v: c=v>>4, b4=(v&15)*4.
    int obase = n * (C_ * NB_) + seg * 64;
#pragma unroll
    for (int i = 0; i < 2; ++i) {
        int v  = i * 256 + t;
        int cc = v >> 4;
        int b4 = (v & 15) * 4;
        nfloat4 o;
        o.x = s_out[cc * 65 + b4 + 0];
        o.y = s_out[cc * 65 + b4 + 1];
        o.z = s_out[cc * 65 + b4 + 2];
        o.w = s_out[cc * 65 + b4 + 3];
        __builtin_nontemporal_store(o, (nfloat4*)&out[obase + cc * NB_ + b4]);
    }
}

// Fallback (R1, known-good): thread per output, full geometry recompute.
__global__ __launch_bounds__(256) void roi_prep(const float* __restrict__ rois,
                                                float* __restrict__ g, int N) {
    int n = blockIdx.x * 256 + threadIdx.x;
    if (n < N) roi_transform(rois, n, g);
}

__global__ __launch_bounds__(256) void rroi_fallback(
    const float* __restrict__ feat, const float* __restrict__ g,
    float* __restrict__ out, int total) {
#pragma clang fp contract(off)
    int idx = blockIdx.x * 256 + threadIdx.x;
    if (idx >= total) return;
    int pw = idx & 63;
    int ph = (idx >> 6) & 7;
    int c  = (idx >> 9) & 31;
    int n  = idx >> 14;
    const float* gg = g + n * 8;
    int   b   = (int)gg[0];
    float M00 = gg[1], M01 = gg[2], M02 = gg[3];
    float M10 = gg[4], M11 = gg[5], M12 = gg[6];
    float pwf  = (float)pw, phf = (float)ph;
    float pwf1 = pwf + 1.0f, phf1 = phf + 1.0f;
    float X0 = (M00 * pwf  + M01 * phf ) + M02;
    float X1 = (M00 * pwf  + M01 * phf1) + M02;
    float X2 = (M00 * pwf1 + M01 * phf ) + M02;
    float X3 = (M00 * pwf1 + M01 * phf1) + M02;
    float Y0 = (M10 * pwf  + M11 * phf ) + M12;
    float Y1 = (M10 * pwf  + M11 * phf1) + M12;
    float Y2 = (M10 * pwf1 + M11 * phf ) + M12;
    float Y3 = (M10 * pwf1 + M11 * phf1) + M12;
    float minX = fminf(fminf(X0, X1), fminf(X2, X3));
    float maxX = fmaxf(fmaxf(X0, X1), fmaxf(X2, X3));
    float minY = fminf(fminf(Y0, Y1), fminf(Y2, Y3));
    float maxY = fmaxf(fmaxf(Y0, Y1), fmaxf(Y2, Y3));
    float left   = fmaxf(floorf(minX + 0.5f), 0.0f);
    float right  = fminf(floorf(maxX + 0.5f), (float)(W_ - 1));
    float top    = fmaxf(floorf(minY + 0.5f), 0.0f);
    float bottom = fminf(floorf(maxY + 0.5f), (float)(H_ - 1));
    float bcx = (left + right) * 0.5f;
    float bcy = (top + bottom) * 0.5f;
    float bl = floorf(bcx), br = ceilf(bcx);
    float bt = floorf(bcy), bb = ceilf(bcy);
    float rx = bcx - bl;
    float ry = bcy - bt;
    const float* fc = feat + (size_t)(b * C_ + c) * HW_;
    auto gat = [&](float yi, float xi) -> float {
        bool valid = (yi > -1.0f) && (xi > -1.0f) && (yi < (float)H_) &&
                     (xi < (float)W_);
        int yc = (int)fminf(fmaxf(yi, 0.0f), (float)(H_ - 1));
        int xc = (int)fminf(fmaxf(xi, 0.0f), (float)(W_ - 1));
        float v = fc[yc * W_ + xc];
        return valid ? v : 0.0f;
    };
    float vlt = gat(bt, bl);
    float vrt = gat(bt, br);
    float vlb = gat(bb, bl);
    float vrb = gat(bb, br);
    float omrx = 1.0f - rx, omry = 1.0f - ry;
    float o = (((omrx * omry) * vlt + (rx * omry) * vrt) + (omrx * ry) * vlb) +
              (rx * ry) * vrb;
    out[idx] = o;
}

extern "C" void kernel_launch(void* const* d_in, const int* in_sizes, int n_in,
                              void* d_out, int out_size, void* d_ws,
                              size_t ws_size, hipStream_t stream) {
    const float* feat = (const float*)d_in[0];
    const float* rois = (const float*)d_in[1];
    float* out = (float*)d_out;
    int N = in_sizes[1] / 6;
    int B = in_sizes[0] / (C_ * HW_);

    size_t gBytes  = ((size_t)N * 8 * sizeof(float) + 255) & ~(size_t)255;
    size_t ftBytes = (size_t)B * HW_ * C_ * sizeof(_Float16);
    size_t needed  = gBytes + ftBytes;

    if (ws_size >= needed) {
        float*    g  = (float*)d_ws;
        _Float16* ft = (_Float16*)((char*)d_ws + gBytes);
        hipLaunchKernelGGL(transpose_nhwc, dim3(HW_ / 64, B), dim3(256), 0,
                           stream, feat, ft, rois, g, N);
        hipLaunchKernelGGL(rroi_nhwc, dim3(N * 8), dim3(256), 0, stream, ft, g,
                           out);
    } else {
        float* g = (float*)d_ws;  // N*8 floats
        hipLaunchKernelGGL(roi_prep, dim3((N + 255) / 256), dim3(256), 0,
                           stream, rois, g, N);
        hipLaunchKernelGGL(rroi_fallback, dim3((out_size + 255) / 256),
                           dim3(256), 0, stream, feat, g, out, out_size);
    }
}